// Round 8
// baseline (593.513 us; speedup 1.0000x reference)
//
#include <hip/hip_runtime.h>
#include <stdint.h>

// ---------- helpers ----------
typedef __attribute__((ext_vector_type(8))) short short8;   // 8 x bf16 (4 VGPRs)
typedef __attribute__((ext_vector_type(4))) float floatx4;  // MFMA accum

__device__ __forceinline__ unsigned short f2bf(float f) {
  union { float f; unsigned int u; } c; c.f = f;
  unsigned int u = c.u;
  unsigned int r = (u + 0x7fffu + ((u >> 16) & 1u)) >> 16;  // RNE
  return (unsigned short)r;
}
__device__ __forceinline__ float bf2f(unsigned short h) {
  union { unsigned int u; float f; } c; c.u = ((unsigned int)h) << 16;
  return c.f;
}

// async global->LDS, 16B per lane. LDS dest is wave-uniform base + lane*16.
__device__ __forceinline__ void load16_to_lds(const void* g, void* l) {
  __builtin_amdgcn_global_load_lds(
      (const __attribute__((address_space(1))) unsigned int*)g,
      (__attribute__((address_space(3))) unsigned int*)l, 16, 0, 0);
}

// ---------- elementwise kernels ----------
__global__ void f32_to_bf16_kernel(const float* __restrict__ in,
                                   unsigned short* __restrict__ out, long n4) {
  long i = blockIdx.x * (long)blockDim.x + threadIdx.x;
  if (i >= n4) return;
  float4 v = ((const float4*)in)[i];
  ushort4 o;
  o.x = f2bf(v.x); o.y = f2bf(v.y); o.z = f2bf(v.z); o.w = f2bf(v.w);
  ((ushort4*)out)[i] = o;
}

__global__ void dequant2_kernel(const float* __restrict__ w1q,
                                const float* __restrict__ s1,
                                const float* __restrict__ w3q,
                                const float* __restrict__ s3,
                                unsigned short* __restrict__ o1,
                                unsigned short* __restrict__ o3,
                                int K, int sK) {
  int n = blockIdx.y;
  int k = blockIdx.x * 1024 + threadIdx.x * 4;
  size_t idx = (size_t)n * K + k;
  int sidx = (n >> 7) * sK + (k >> 7);
  float sc1 = s1[sidx], sc3 = s3[sidx];
  float4 v1 = *(const float4*)(w1q + idx);
  float4 v3 = *(const float4*)(w3q + idx);
  ushort4 a, b;
  a.x = f2bf(v1.x * sc1); a.y = f2bf(v1.y * sc1);
  a.z = f2bf(v1.z * sc1); a.w = f2bf(v1.w * sc1);
  b.x = f2bf(v3.x * sc3); b.y = f2bf(v3.y * sc3);
  b.z = f2bf(v3.z * sc3); b.w = f2bf(v3.w * sc3);
  *(ushort4*)(o1 + idx) = a;
  *(ushort4*)(o3 + idx) = b;
}

__global__ void dequant1_kernel(const float* __restrict__ wq,
                                const float* __restrict__ s,
                                unsigned short* __restrict__ out,
                                int K, int sK) {
  int n = blockIdx.y;
  int k = blockIdx.x * 1024 + threadIdx.x * 4;
  size_t idx = (size_t)n * K + k;
  float sc = s[(n >> 7) * sK + (k >> 7)];
  float4 v = *(const float4*)(wq + idx);
  ushort4 o;
  o.x = f2bf(v.x * sc); o.y = f2bf(v.y * sc);
  o.z = f2bf(v.z * sc); o.w = f2bf(v.w * sc);
  *(ushort4*)(out + idx) = o;
}

// ---------- LDS swizzle (R6-verified: conflicts -> 0) ----------
// Tile = rows x 8 kblks (kblk = 16B). unit(row,kblk) = row*8 + (kblk ^ (row&7)).

// ---------- merged dual GEMM + silu (R6-exact: 970 TF measured) ----------
// 512 threads = 8 waves (2m x 4n); wave-tile 64x32; BK=64; swizzled LDS.
// Regs ~124/wave -> 4 waves/SIMD; 2 blocks/CU -> 16 waves/CU (40% occ).
// R7 showed 64x64 wave-tile (236 regs -> 8 waves/CU) regresses: occupancy
// beats LDS-traffic reduction for the fused kernel.
__global__ __launch_bounds__(512, 4) void dual_gemm_silu(
    const unsigned short* __restrict__ A,   // [M,K] bf16 (x)
    const unsigned short* __restrict__ B1,  // [N,K] bf16 (w1)
    const unsigned short* __restrict__ B3,  // [N,K] bf16 (w3)
    unsigned short* __restrict__ C,         // [M,N] bf16 fused
    int M, int N, int K) {
  __shared__ unsigned short As[128 * 64];   // 16 KB
  __shared__ unsigned short B1s[128 * 64];  // 16 KB
  __shared__ unsigned short B3s[128 * 64];  // 16 KB

  const int tid = threadIdx.x;
  const int lane = tid & 63;
  const int wave = tid >> 6;      // 0..7
  const int wm = wave >> 2;       // 0..1  (M 64-half)
  const int wn = wave & 3;        // 0..3  (N 32-quarter)
  const int m0 = blockIdx.y * 128, n0 = blockIdx.x * 128;

  const int s0 = tid, s1 = tid + 512;
  const int r0 = s0 >> 3, c0 = ((s0 & 7) ^ (r0 & 7)) * 8;
  const int r1 = s1 >> 3, c1 = ((s1 & 7) ^ (r1 & 7)) * 8;

  const int q = lane >> 4;        // 0..3
  const int r16 = lane & 15;
  const int rx = r16 & 7;

  floatx4 acc_g[4][2], acc_u[4][2];
#pragma unroll
  for (int i = 0; i < 4; i++)
#pragma unroll
    for (int j = 0; j < 2; j++) {
      acc_g[i][j] = (floatx4){0.f, 0.f, 0.f, 0.f};
      acc_u[i][j] = (floatx4){0.f, 0.f, 0.f, 0.f};
    }

  const unsigned short* ag0 = A + (size_t)(m0 + r0) * K + c0;
  const unsigned short* ag1 = A + (size_t)(m0 + r1) * K + c1;
  const unsigned short* b1g0 = B1 + (size_t)(n0 + r0) * K + c0;
  const unsigned short* b1g1 = B1 + (size_t)(n0 + r1) * K + c1;
  const unsigned short* b3g0 = B3 + (size_t)(n0 + r0) * K + c0;
  const unsigned short* b3g1 = B3 + (size_t)(n0 + r1) * K + c1;

  for (int k0 = 0; k0 < K; k0 += 64) {
    load16_to_lds(ag0 + k0, &As[s0 * 8]);
    load16_to_lds(ag1 + k0, &As[s1 * 8]);
    load16_to_lds(b1g0 + k0, &B1s[s0 * 8]);
    load16_to_lds(b1g1 + k0, &B1s[s1 * 8]);
    load16_to_lds(b3g0 + k0, &B3s[s0 * 8]);
    load16_to_lds(b3g1 + k0, &B3s[s1 * 8]);
    __syncthreads();

#pragma unroll
    for (int kh = 0; kh < 2; kh++) {
      const int kq = kh * 4 + q;
      short8 a[4], b1v[2], b3v[2];
#pragma unroll
      for (int t = 0; t < 4; t++) {
        int row = wm * 64 + t * 16 + r16;
        a[t] = *(const short8*)&As[(row * 8 + (kq ^ rx)) * 8];
      }
#pragma unroll
      for (int j = 0; j < 2; j++) {
        int row = wn * 32 + j * 16 + r16;
        int u = (row * 8 + (kq ^ rx)) * 8;
        b1v[j] = *(const short8*)&B1s[u];
        b3v[j] = *(const short8*)&B3s[u];
      }
#pragma unroll
      for (int i = 0; i < 4; i++)
#pragma unroll
        for (int j = 0; j < 2; j++) {
          acc_g[i][j] = __builtin_amdgcn_mfma_f32_16x16x32_bf16(
              a[i], b1v[j], acc_g[i][j], 0, 0, 0);
          acc_u[i][j] = __builtin_amdgcn_mfma_f32_16x16x32_bf16(
              a[i], b3v[j], acc_u[i][j], 0, 0, 0);
        }
    }
    __syncthreads();
  }

  // epilogue: D col = lane&15, row = quad*4 + reg (m89/m91-verified)
#pragma unroll
  for (int i = 0; i < 4; i++) {
    int row0 = m0 + wm * 64 + i * 16 + q * 4;
#pragma unroll
    for (int j = 0; j < 2; j++) {
      int col = n0 + wn * 32 + j * 16 + r16;
#pragma unroll
      for (int rr = 0; rr < 4; rr++) {
        float gv = acc_g[i][j][rr];
        float uv = acc_u[i][j][rr];
        float sv = gv / (1.f + __expf(-gv)) * uv;
        C[(size_t)(row0 + rr) * N + col] = f2bf(sv);
      }
    }
  }
}

// ---------- GEMM3: C[M,N] = A[M,K] * B[N,K]^T, bf16 in, fp32 out ----------
// R8: 128x64 block tile -> grid 1024 blocks (was 512 = only 2/CU). 256
// threads = 4 waves (2m x 2n), wave-tile 64x32: acc 32 AGPR + ~50 VGPR
// ≈ 82 regs -> 4+ waves/SIMD; LDS 24 KB -> 4 blocks/CU = 16 waves/CU.
__global__ __launch_bounds__(256, 4) void gemm_nt_f32_n64(
    const unsigned short* __restrict__ A,  // [M,K] bf16
    const unsigned short* __restrict__ B,  // [N,K] bf16
    float* __restrict__ C,                 // [M,N] fp32
    int M, int N, int K) {
  __shared__ unsigned short As[128 * 64];  // 16 KB
  __shared__ unsigned short Bs[64 * 64];   // 8 KB

  const int tid = threadIdx.x;
  const int lane = tid & 63;
  const int wave = tid >> 6;
  const int wm = wave >> 1;       // 0..1 (M 64-half)
  const int wn = wave & 1;        // 0..1 (N 32-half)
  const int m0 = blockIdx.y * 128, n0 = blockIdx.x * 64;

  // A staging: 1024 units, thread t fills t and t+256 ... t+768 (4 units)
  // B staging: 512 units, thread t fills t and t+256 (2 units)
  const int q = lane >> 4;
  const int r16 = lane & 15;
  const int rx = r16 & 7;

  floatx4 acc[4][2];
#pragma unroll
  for (int i = 0; i < 4; i++)
#pragma unroll
    for (int j = 0; j < 2; j++) acc[i][j] = (floatx4){0.f, 0.f, 0.f, 0.f};

  int aoff[4], adst[4];
#pragma unroll
  for (int p = 0; p < 4; p++) {
    int u = tid + 256 * p;
    int r = u >> 3;
    int c = ((u & 7) ^ (r & 7)) * 8;
    aoff[p] = r * K + c;
    adst[p] = u * 8;
  }
  int boff[2], bdst[2];
#pragma unroll
  for (int p = 0; p < 2; p++) {
    int u = tid + 256 * p;
    int r = u >> 3;
    int c = ((u & 7) ^ (r & 7)) * 8;
    boff[p] = r * K + c;
    bdst[p] = u * 8;
  }

  const unsigned short* Abase = A + (size_t)m0 * K;
  const unsigned short* Bbase = B + (size_t)n0 * K;

  for (int k0 = 0; k0 < K; k0 += 64) {
#pragma unroll
    for (int p = 0; p < 4; p++)
      load16_to_lds(Abase + aoff[p] + k0, &As[adst[p]]);
#pragma unroll
    for (int p = 0; p < 2; p++)
      load16_to_lds(Bbase + boff[p] + k0, &Bs[bdst[p]]);
    __syncthreads();

#pragma unroll
    for (int kh = 0; kh < 2; kh++) {
      const int kq = kh * 4 + q;
      short8 a[4], b[2];
#pragma unroll
      for (int t = 0; t < 4; t++) {
        int row = wm * 64 + t * 16 + r16;
        a[t] = *(const short8*)&As[(row * 8 + (kq ^ rx)) * 8];
      }
#pragma unroll
      for (int j = 0; j < 2; j++) {
        int row = wn * 32 + j * 16 + r16;
        b[j] = *(const short8*)&Bs[(row * 8 + (kq ^ rx)) * 8];
      }
#pragma unroll
      for (int i = 0; i < 4; i++)
#pragma unroll
        for (int j = 0; j < 2; j++)
          acc[i][j] = __builtin_amdgcn_mfma_f32_16x16x32_bf16(
              a[i], b[j], acc[i][j], 0, 0, 0);
    }
    __syncthreads();
  }

#pragma unroll
  for (int i = 0; i < 4; i++) {
    int row0 = m0 + wm * 64 + i * 16 + q * 4;
#pragma unroll
    for (int j = 0; j < 2; j++) {
      int col = n0 + wn * 32 + j * 16 + r16;
#pragma unroll
      for (int rr = 0; rr < 4; rr++)
        C[(size_t)(row0 + rr) * N + col] = acc[i][j][rr];
    }
  }
}

// ---------- launch ----------
extern "C" void kernel_launch(void* const* d_in, const int* in_sizes, int n_in,
                              void* d_out, int out_size, void* d_ws, size_t ws_size,
                              hipStream_t stream) {
  const float* x = (const float*)d_in[0];
  const float* w1q = (const float*)d_in[1];
  const float* w1s = (const float*)d_in[2];
  const float* w3q = (const float*)d_in[3];
  const float* w3s = (const float*)d_in[4];
  const float* w2q = (const float*)d_in[5];
  const float* w2s = (const float*)d_in[6];

  const int T = 4096, H = 2048, F = 7168;

  char* ws = (char*)d_ws;
  unsigned short* xb  = (unsigned short*)ws;  ws += (size_t)T * H * 2;   // 16.8 MB
  unsigned short* w1b = (unsigned short*)ws;  ws += (size_t)F * H * 2;   // 29.4 MB
  unsigned short* w3b = (unsigned short*)ws;  ws += (size_t)F * H * 2;   // 29.4 MB
  unsigned short* w2b = (unsigned short*)ws;  ws += (size_t)H * F * 2;   // 29.4 MB
  unsigned short* g   = (unsigned short*)ws;  ws += (size_t)T * F * 2;   // 58.7 MB

  long xn4 = (long)T * H / 4;

  f32_to_bf16_kernel<<<(xn4 + 255) / 256, 256, 0, stream>>>(x, xb, xn4);
  dequant2_kernel<<<dim3(H / 1024, F), 256, 0, stream>>>(
      w1q, w1s, w3q, w3s, w1b, w3b, H, H / 128);
  dequant1_kernel<<<dim3(F / 1024, H), 256, 0, stream>>>(
      w2q, w2s, w2b, F, F / 128);

  // g = silu(x @ w1^T) * (x @ w3^T)
  dual_gemm_silu<<<dim3(F / 128, T / 128), 512, 0, stream>>>(xb, w1b, w3b, g, T, F, H);

  // out = g @ w2^T  (fp32 out)
  gemm_nt_f32_n64<<<dim3(H / 64, T / 128), 256, 0, stream>>>(g, w2b, (float*)d_out, T, H, F);
}

// Round 9
// 582.929 us; speedup vs baseline: 1.0182x; 1.0182x over previous
//
#include <hip/hip_runtime.h>
#include <stdint.h>

// ---------- helpers ----------
typedef __attribute__((ext_vector_type(8))) short short8;   // 8 x bf16 (4 VGPRs)
typedef __attribute__((ext_vector_type(4))) float floatx4;  // MFMA accum

__device__ __forceinline__ unsigned short f2bf(float f) {
  union { float f; unsigned int u; } c; c.f = f;
  unsigned int u = c.u;
  unsigned int r = (u + 0x7fffu + ((u >> 16) & 1u)) >> 16;  // RNE
  return (unsigned short)r;
}
__device__ __forceinline__ float bf2f(unsigned short h) {
  union { unsigned int u; float f; } c; c.u = ((unsigned int)h) << 16;
  return c.f;
}

// async global->LDS, 16B per lane. LDS dest is wave-uniform base + lane*16.
__device__ __forceinline__ void load16_to_lds(const void* g, void* l) {
  __builtin_amdgcn_global_load_lds(
      (const __attribute__((address_space(1))) unsigned int*)g,
      (__attribute__((address_space(3))) unsigned int*)l, 16, 0, 0);
}

// ---------- elementwise kernels ----------
__global__ void f32_to_bf16_kernel(const float* __restrict__ in,
                                   unsigned short* __restrict__ out, long n4) {
  long i = blockIdx.x * (long)blockDim.x + threadIdx.x;
  if (i >= n4) return;
  float4 v = ((const float4*)in)[i];
  ushort4 o;
  o.x = f2bf(v.x); o.y = f2bf(v.y); o.z = f2bf(v.z); o.w = f2bf(v.w);
  ((ushort4*)out)[i] = o;
}

__global__ void dequant2_kernel(const float* __restrict__ w1q,
                                const float* __restrict__ s1,
                                const float* __restrict__ w3q,
                                const float* __restrict__ s3,
                                unsigned short* __restrict__ o1,
                                unsigned short* __restrict__ o3,
                                int K, int sK) {
  int n = blockIdx.y;
  int k = blockIdx.x * 1024 + threadIdx.x * 4;
  size_t idx = (size_t)n * K + k;
  int sidx = (n >> 7) * sK + (k >> 7);
  float sc1 = s1[sidx], sc3 = s3[sidx];
  float4 v1 = *(const float4*)(w1q + idx);
  float4 v3 = *(const float4*)(w3q + idx);
  ushort4 a, b;
  a.x = f2bf(v1.x * sc1); a.y = f2bf(v1.y * sc1);
  a.z = f2bf(v1.z * sc1); a.w = f2bf(v1.w * sc1);
  b.x = f2bf(v3.x * sc3); b.y = f2bf(v3.y * sc3);
  b.z = f2bf(v3.z * sc3); b.w = f2bf(v3.w * sc3);
  *(ushort4*)(o1 + idx) = a;
  *(ushort4*)(o3 + idx) = b;
}

__global__ void dequant1_kernel(const float* __restrict__ wq,
                                const float* __restrict__ s,
                                unsigned short* __restrict__ out,
                                int K, int sK) {
  int n = blockIdx.y;
  int k = blockIdx.x * 1024 + threadIdx.x * 4;
  size_t idx = (size_t)n * K + k;
  float sc = s[(n >> 7) * sK + (k >> 7)];
  float4 v = *(const float4*)(wq + idx);
  ushort4 o;
  o.x = f2bf(v.x * sc); o.y = f2bf(v.y * sc);
  o.z = f2bf(v.z * sc); o.w = f2bf(v.w * sc);
  *(ushort4*)(out + idx) = o;
}

// ---------- LDS swizzle (R6-verified: conflicts -> 0) ----------
// Tile = rows x 8 kblks (kblk = 16B). unit(row,kblk) = row*8 + (kblk ^ (row&7)).

// ---------- merged dual GEMM + silu (R6-exact: 970 TF measured) ----------
// 512 threads = 8 waves (2m x 4n); wave-tile 64x32; BK=64; swizzled LDS.
__global__ __launch_bounds__(512, 4) void dual_gemm_silu(
    const unsigned short* __restrict__ A,   // [M,K] bf16 (x)
    const unsigned short* __restrict__ B1,  // [N,K] bf16 (w1)
    const unsigned short* __restrict__ B3,  // [N,K] bf16 (w3)
    unsigned short* __restrict__ C,         // [M,N] bf16 fused
    int M, int N, int K) {
  __shared__ unsigned short As[128 * 64];   // 16 KB
  __shared__ unsigned short B1s[128 * 64];  // 16 KB
  __shared__ unsigned short B3s[128 * 64];  // 16 KB

  const int tid = threadIdx.x;
  const int lane = tid & 63;
  const int wave = tid >> 6;      // 0..7
  const int wm = wave >> 2;       // 0..1  (M 64-half)
  const int wn = wave & 3;        // 0..3  (N 32-quarter)
  const int m0 = blockIdx.y * 128, n0 = blockIdx.x * 128;

  const int s0 = tid, s1 = tid + 512;
  const int r0 = s0 >> 3, c0 = ((s0 & 7) ^ (r0 & 7)) * 8;
  const int r1 = s1 >> 3, c1 = ((s1 & 7) ^ (r1 & 7)) * 8;

  const int q = lane >> 4;        // 0..3
  const int r16 = lane & 15;
  const int rx = r16 & 7;

  floatx4 acc_g[4][2], acc_u[4][2];
#pragma unroll
  for (int i = 0; i < 4; i++)
#pragma unroll
    for (int j = 0; j < 2; j++) {
      acc_g[i][j] = (floatx4){0.f, 0.f, 0.f, 0.f};
      acc_u[i][j] = (floatx4){0.f, 0.f, 0.f, 0.f};
    }

  const unsigned short* ag0 = A + (size_t)(m0 + r0) * K + c0;
  const unsigned short* ag1 = A + (size_t)(m0 + r1) * K + c1;
  const unsigned short* b1g0 = B1 + (size_t)(n0 + r0) * K + c0;
  const unsigned short* b1g1 = B1 + (size_t)(n0 + r1) * K + c1;
  const unsigned short* b3g0 = B3 + (size_t)(n0 + r0) * K + c0;
  const unsigned short* b3g1 = B3 + (size_t)(n0 + r1) * K + c1;

  for (int k0 = 0; k0 < K; k0 += 64) {
    load16_to_lds(ag0 + k0, &As[s0 * 8]);
    load16_to_lds(ag1 + k0, &As[s1 * 8]);
    load16_to_lds(b1g0 + k0, &B1s[s0 * 8]);
    load16_to_lds(b1g1 + k0, &B1s[s1 * 8]);
    load16_to_lds(b3g0 + k0, &B3s[s0 * 8]);
    load16_to_lds(b3g1 + k0, &B3s[s1 * 8]);
    __syncthreads();

#pragma unroll
    for (int kh = 0; kh < 2; kh++) {
      const int kq = kh * 4 + q;
      short8 a[4], b1v[2], b3v[2];
#pragma unroll
      for (int t = 0; t < 4; t++) {
        int row = wm * 64 + t * 16 + r16;
        a[t] = *(const short8*)&As[(row * 8 + (kq ^ rx)) * 8];
      }
#pragma unroll
      for (int j = 0; j < 2; j++) {
        int row = wn * 32 + j * 16 + r16;
        int u = (row * 8 + (kq ^ rx)) * 8;
        b1v[j] = *(const short8*)&B1s[u];
        b3v[j] = *(const short8*)&B3s[u];
      }
#pragma unroll
      for (int i = 0; i < 4; i++)
#pragma unroll
        for (int j = 0; j < 2; j++) {
          acc_g[i][j] = __builtin_amdgcn_mfma_f32_16x16x32_bf16(
              a[i], b1v[j], acc_g[i][j], 0, 0, 0);
          acc_u[i][j] = __builtin_amdgcn_mfma_f32_16x16x32_bf16(
              a[i], b3v[j], acc_u[i][j], 0, 0, 0);
        }
    }
    __syncthreads();
  }

  // epilogue: D col = lane&15, row = quad*4 + reg (m89/m91-verified)
#pragma unroll
  for (int i = 0; i < 4; i++) {
    int row0 = m0 + wm * 64 + i * 16 + q * 4;
#pragma unroll
    for (int j = 0; j < 2; j++) {
      int col = n0 + wn * 32 + j * 16 + r16;
#pragma unroll
      for (int rr = 0; rr < 4; rr++) {
        float gv = acc_g[i][j][rr];
        float uv = acc_u[i][j][rr];
        float sv = gv / (1.f + __expf(-gv)) * uv;
        C[(size_t)(row0 + rr) * N + col] = f2bf(sv);
      }
    }
  }
}

// ---------- GEMM3 split-K: C[M,N] += A[M,K] * B[N,K]^T over K-half ----------
// Best-measured gemm3 structure (R6's 4-wave 128x128, 64x64 wave-tile,
// reads/MFMA = 0.5) + split-K=2 via blockIdx.z: grid 1024 blocks (~3
// resident/CU = 12 waves/CU vs 8 before — gemm3 was latency-bound at 2
// blocks/CU). Epilogue: unsafeAtomicAdd (native global_atomic_add_f32);
// exactly 2 commutative f32 adds per location -> deterministic. d_out is
// zeroed by hipMemsetAsync before launch.
__global__ __launch_bounds__(256, 2) void gemm_nt_f32_sk(
    const unsigned short* __restrict__ A,  // [M,K] bf16
    const unsigned short* __restrict__ B,  // [N,K] bf16
    float* __restrict__ C,                 // [M,N] fp32 (pre-zeroed)
    int M, int N, int K) {
  __shared__ unsigned short As[128 * 64];
  __shared__ unsigned short Bs[128 * 64];

  const int tid = threadIdx.x;
  const int lane = tid & 63;
  const int wave = tid >> 6;
  const int wm = wave >> 1;       // 0..1
  const int wn = wave & 1;        // 0..1
  const int m0 = blockIdx.y * 128, n0 = blockIdx.x * 128;
  const int kbase = blockIdx.z * (K >> 1);
  const int kend = kbase + (K >> 1);

  int soff[4], sdst[4];
#pragma unroll
  for (int p = 0; p < 4; p++) {
    int u = tid + 256 * p;
    int r = u >> 3;
    int c = ((u & 7) ^ (r & 7)) * 8;
    soff[p] = r * K + c;
    sdst[p] = u * 8;
  }

  const int q = lane >> 4;
  const int r16 = lane & 15;
  const int rx = r16 & 7;

  floatx4 acc[4][4];
#pragma unroll
  for (int i = 0; i < 4; i++)
#pragma unroll
    for (int j = 0; j < 4; j++) acc[i][j] = (floatx4){0.f, 0.f, 0.f, 0.f};

  const unsigned short* Abase = A + (size_t)m0 * K;
  const unsigned short* Bbase = B + (size_t)n0 * K;

  for (int k0 = kbase; k0 < kend; k0 += 64) {
#pragma unroll
    for (int p = 0; p < 4; p++) {
      load16_to_lds(Abase + soff[p] + k0, &As[sdst[p]]);
      load16_to_lds(Bbase + soff[p] + k0, &Bs[sdst[p]]);
    }
    __syncthreads();

#pragma unroll
    for (int kh = 0; kh < 2; kh++) {
      const int kq = kh * 4 + q;
      short8 a[4], b[4];
#pragma unroll
      for (int t = 0; t < 4; t++) {
        int row = wm * 64 + t * 16 + r16;
        a[t] = *(const short8*)&As[(row * 8 + (kq ^ rx)) * 8];
      }
#pragma unroll
      for (int j = 0; j < 4; j++) {
        int row = wn * 64 + j * 16 + r16;
        b[j] = *(const short8*)&Bs[(row * 8 + (kq ^ rx)) * 8];
      }
#pragma unroll
      for (int i = 0; i < 4; i++)
#pragma unroll
        for (int j = 0; j < 4; j++)
          acc[i][j] = __builtin_amdgcn_mfma_f32_16x16x32_bf16(
              a[i], b[j], acc[i][j], 0, 0, 0);
    }
    __syncthreads();
  }

#pragma unroll
  for (int i = 0; i < 4; i++) {
    int row0 = m0 + wm * 64 + i * 16 + q * 4;
#pragma unroll
    for (int j = 0; j < 4; j++) {
      int col = n0 + wn * 64 + j * 16 + r16;
#pragma unroll
      for (int rr = 0; rr < 4; rr++)
        unsafeAtomicAdd(&C[(size_t)(row0 + rr) * N + col], acc[i][j][rr]);
    }
  }
}

// ---------- launch ----------
extern "C" void kernel_launch(void* const* d_in, const int* in_sizes, int n_in,
                              void* d_out, int out_size, void* d_ws, size_t ws_size,
                              hipStream_t stream) {
  const float* x = (const float*)d_in[0];
  const float* w1q = (const float*)d_in[1];
  const float* w1s = (const float*)d_in[2];
  const float* w3q = (const float*)d_in[3];
  const float* w3s = (const float*)d_in[4];
  const float* w2q = (const float*)d_in[5];
  const float* w2s = (const float*)d_in[6];

  const int T = 4096, H = 2048, F = 7168;

  char* ws = (char*)d_ws;
  unsigned short* xb  = (unsigned short*)ws;  ws += (size_t)T * H * 2;   // 16.8 MB
  unsigned short* w1b = (unsigned short*)ws;  ws += (size_t)F * H * 2;   // 29.4 MB
  unsigned short* w3b = (unsigned short*)ws;  ws += (size_t)F * H * 2;   // 29.4 MB
  unsigned short* w2b = (unsigned short*)ws;  ws += (size_t)H * F * 2;   // 29.4 MB
  unsigned short* g   = (unsigned short*)ws;  ws += (size_t)T * F * 2;   // 58.7 MB

  long xn4 = (long)T * H / 4;

  f32_to_bf16_kernel<<<(xn4 + 255) / 256, 256, 0, stream>>>(x, xb, xn4);
  dequant2_kernel<<<dim3(H / 1024, F), 256, 0, stream>>>(
      w1q, w1s, w3q, w3s, w1b, w3b, H, H / 128);
  dequant1_kernel<<<dim3(F / 1024, H), 256, 0, stream>>>(
      w2q, w2s, w2b, F, F / 128);

  // g = silu(x @ w1^T) * (x @ w3^T)
  dual_gemm_silu<<<dim3(F / 128, T / 128), 512, 0, stream>>>(xb, w1b, w3b, g, T, F, H);

  // out = g @ w2^T  (fp32, split-K=2 accumulated via atomics)
  hipMemsetAsync(d_out, 0, (size_t)T * H * 4, stream);
  gemm_nt_f32_sk<<<dim3(H / 128, T / 128, 2), 256, 0, stream>>>(
      g, w2b, (float*)d_out, T, H, F);
}